// Round 9
// baseline (165.078 us; speedup 1.0000x reference)
//
#include <hip/hip_runtime.h>

// Fused EdgeNetwork on 32x32x16 MFMA: one wave = one 32-edge x 32-col tile.
//   OUT = P @ W:  P[e, b*32+j] = bond[e,b]*nb[e,j]   (b=16 -> bias row, w=1)
//   W[b*32+j, i] = K[b, i*32+j]  staged once in LDS as packed B-fragments.
// vs R8 (16x16 col-half split): halves wave-tiles (12500), halves A-frag VALU
// and nb-gather instruction count. 2-deep pipeline. fp32 atomics direct to out.

typedef _Float16 half8 __attribute__((ext_vector_type(8)));
typedef _Float16 half4t __attribute__((ext_vector_type(4)));
typedef float float16v __attribute__((ext_vector_type(16)));

constexpr int NA = 100000;
constexpr int E  = 400000;
constexpr int TILES = E / 32;          // 12500
constexpr int NBLK  = 1024;            // 4 blocks/CU (LDS-capped)
constexpr int NWAVE = NBLK * 4;        // 4096 persistent waves

constexpr size_t OFF_ATOMH = 0;                   // _Float16[NA*32]  (6.4 MB)
constexpr size_t OFF_BONDH = (size_t)NA * 32 * 2; // _Float16[E*16]  (12.8 MB)

constexpr int NZ4 = NA * 32 / 4;   // out zeroing, float4 units
constexpr int NA4 = NA * 32 / 4;   // atom convert, float4 units
constexpr int NB4 = E * 16 / 4;    // bond convert, float4 units
constexpr int PREP_TOT = NZ4 + NA4 + NB4;

__global__ void k_prep(const float* __restrict__ atom,
                       const float* __restrict__ bond,
                       float4* __restrict__ outz,
                       half4t* __restrict__ atomh4,
                       half4t* __restrict__ bondh4) {
  int i = blockIdx.x * blockDim.x + threadIdx.x;
  if (i < NZ4) {
    outz[i] = make_float4(0.f, 0.f, 0.f, 0.f);
  } else if (i < NZ4 + NA4) {
    int k = i - NZ4;
    float4 v = ((const float4*)atom)[k];
    half4t hh = { (_Float16)v.x, (_Float16)v.y, (_Float16)v.z, (_Float16)v.w };
    atomh4[k] = hh;
  } else if (i < PREP_TOT) {
    int k = i - NZ4 - NA4;
    float4 v = ((const float4*)bond)[k];
    half4t hh = { (_Float16)v.x, (_Float16)v.y, (_Float16)v.z, (_Float16)v.w };
    bondh4[k] = hh;
  }
}

static __device__ inline half8 splat8(_Float16 v) {
  half8 r = {v, v, v, v, v, v, v, v};
  return r;
}

__global__ __launch_bounds__(256, 3)
void edge_fused(const _Float16* __restrict__ atomh,
                const _Float16* __restrict__ bondh,
                const int* __restrict__ pairs,
                const float* __restrict__ Kmat,
                const float* __restrict__ bias,
                float* __restrict__ out)
{
  // B-fragments for 34 MFMA steps (s = 2*b + half): element i of lane l is
  // W[k = b*32 + half*16 + (l>>5)*8 + i][n = l&31].
  __shared__ half8 Wlds[34 * 64];    // 34816 B

  const int tid  = threadIdx.x;
  const int lane = tid & 63;
  const int m    = lane & 31;        // edge-within-tile (A row, C col owner)
  const int hi   = lane >> 5;        // lane half
  const int j0   = hi * 8;

  for (int idx = tid; idx < 34 * 64; idx += 256) {
    const int s  = idx >> 6;         // 0..33
    const int l  = idx & 63;
    const int b  = s >> 1, half = s & 1;
    const int n  = l & 31;
    const int k0 = half * 16 + (l >> 5) * 8;
    const float* src = (b < 16) ? (Kmat + b * 1024 + n * 32 + k0)
                                : (bias + n * 32 + k0);
    float4 v0 = *(const float4*)(src);
    float4 v1 = *(const float4*)(src + 4);
    half8 w = { (_Float16)v0.x, (_Float16)v0.y, (_Float16)v0.z, (_Float16)v0.w,
                (_Float16)v1.x, (_Float16)v1.y, (_Float16)v1.z, (_Float16)v1.w };
    Wlds[idx] = w;
  }
  __syncthreads();

  const int wid = blockIdx.x * 4 + (tid >> 6);
  const int2* pairs2 = (const int2*)pairs;

  auto ldpv = [&](int t) -> int2 {
    const int tc = t < TILES ? t : TILES - 1;
    int2 v = make_int2(0, 0);
    if (lane < 32) v = pairs2[tc * 32 + lane];
    return v;
  };

  // ---- Pipeline prologue: stage tile `wid`, indices for wid+NWAVE in flight.
  int2 pv0 = ldpv(wid);
  int2 pv1 = ldpv(wid + NWAVE);

  half8 nbLo_c, nbHi_c, bd0_c, bd1_c;
  {
    const int a = __shfl(pv0.y, m);
    const _Float16* ar = atomh + (size_t)a * 32;
    nbLo_c = *(const half8*)(ar + j0);
    nbHi_c = *(const half8*)(ar + 16 + j0);
    const _Float16* br = bondh + (size_t)(wid * 32 + m) * 16;
    bd0_c = *(const half8*)(br);
    bd1_c = *(const half8*)(br + 8);
  }

  for (int t = wid; t < TILES; t += NWAVE) {
    const int tn = t + NWAVE;

    // ---- Stage next tile (gathers in flight over this tile's compute).
    half8 nbLo_n, nbHi_n, bd0_n, bd1_n;
    {
      const int a = __shfl(pv1.y, m);
      const _Float16* ar = atomh + (size_t)a * 32;
      nbLo_n = *(const half8*)(ar + j0);
      nbHi_n = *(const half8*)(ar + 16 + j0);
      const int tc = tn < TILES ? tn : TILES - 1;
      const _Float16* br = bondh + (size_t)(tc * 32 + m) * 16;
      bd0_n = *(const half8*)(br);
      bd1_n = *(const half8*)(br + 8);
    }
    const int2 pv2 = ldpv(tn + NWAVE);

    // ---- Compute current tile: 34 MFMAs (17 b-steps x 2 K-halves).
    float16v acc = {0.f,0.f,0.f,0.f, 0.f,0.f,0.f,0.f,
                    0.f,0.f,0.f,0.f, 0.f,0.f,0.f,0.f};
    #pragma unroll
    for (int b = 0; b < 16; ++b) {
      const _Float16 bb = (b < 8) ? bd0_c[b] : bd1_c[b - 8];
      const half8 s8 = splat8(bb);
      const half8 aLo = nbLo_c * s8;
      const half8 aHi = nbHi_c * s8;
      acc = __builtin_amdgcn_mfma_f32_32x32x16_f16(aLo, Wlds[(2*b)   * 64 + lane], acc, 0, 0, 0);
      acc = __builtin_amdgcn_mfma_f32_32x32x16_f16(aHi, Wlds[(2*b+1) * 64 + lane], acc, 0, 0, 0);
    }
    // Bias step (bond weight == 1).
    acc = __builtin_amdgcn_mfma_f32_32x32x16_f16(nbLo_c, Wlds[32 * 64 + lane], acc, 0, 0, 0);
    acc = __builtin_amdgcn_mfma_f32_32x32x16_f16(nbHi_c, Wlds[33 * 64 + lane], acc, 0, 0, 0);

    // ---- Epilogue: C[row][col], col = m, row = (r&3) + 8*(r>>2) + 4*hi.
    #pragma unroll
    for (int r = 0; r < 16; ++r) {
      const int row = (r & 3) + 8 * (r >> 2) + 4 * hi;
      const int s0  = __shfl(pv0.x, row);
      atomicAdd(out + (size_t)s0 * 32 + m, acc[r]);
    }

    // ---- Rotate pipeline registers.
    pv0 = pv1; pv1 = pv2;
    nbLo_c = nbLo_n; nbHi_c = nbHi_n;
    bd0_c = bd0_n;   bd1_c = bd1_n;
  }
}

extern "C" void kernel_launch(void* const* d_in, const int* in_sizes, int n_in,
                              void* d_out, int out_size, void* d_ws, size_t ws_size,
                              hipStream_t stream) {
  const float* atom  = (const float*)d_in[0];   // (100000, 32) f32
  const float* bondf = (const float*)d_in[1];   // (400000, 16) f32
  const int*   pairs = (const int*)d_in[2];     // (400000, 2) int32
  const float* Kmat  = (const float*)d_in[3];   // (16, 1024) f32
  const float* bias  = (const float*)d_in[4];   // (1024,) f32
  float* out = (float*)d_out;                   // (100000, 32) f32

  _Float16* atomh = (_Float16*)((char*)d_ws + OFF_ATOMH);
  _Float16* bondh = (_Float16*)((char*)d_ws + OFF_BONDH);

  k_prep<<<(PREP_TOT + 255) / 256, 256, 0, stream>>>(
      atom, bondf, (float4*)out, (half4t*)atomh, (half4t*)bondh);
  edge_fused<<<NBLK, 256, 0, stream>>>(atomh, bondh, pairs, Kmat, bias, out);
}